// Round 5
// baseline (180.861 us; speedup 1.0000x reference)
//
#include <hip/hip_runtime.h>
#include <math.h>

// Problem constants (fixed instance: bs=32, S=512, E=512, T=2048)
#define BS 32
#define S_TOK 512
#define E_DIM 512
#define T_FR 2048
// exp cut: dropped softmax terms < e^-25 of the max term. Output perturbation
// ~1e-10 abs. Check threshold is 0.108 (bf16-grain ref); absmax 0.0156 is the
// ref-rounding floor.
#define THRESH -25.0f

// NOTE: durations never zero -> reference's MASK_FILL branch is identity.

// ROUND 4 POST-MORTEM: occupancy gave only -3.5us. Four structural rounds,
// kernel pinned ~76us vs ~25-30us memory floor, INVARIANT under internal
// schedule changes. The invariant: barrier-locked phase structure. All
// resident blocks run identical-length preamble->compute->store phases in
// lockstep -> HBM write port sees bursts at ~1/3 duty -> effective ~2 TB/s
// (the fill, barrier-free, hits 6.8 TB/s on the same buffer).
// ROUND 5: wave-autonomous streaming. Hot kernel has ZERO barriers, ZERO LDS;
// each 64-lane wave owns 2 frames, reads precomputed per-frame meta, computes
// exp-weights inline in the token loop, streams its 4KB of output on its own
// schedule. Waves drift -> stores time-smoothed like the fill's. Meta comes
// from the round-0 verified scan/meta kernels (restored verbatim; ~5us total).

typedef float vfloat4 __attribute__((ext_vector_type(4)));

struct RowMeta { float m; float inv_l; int lo; int cnt; };

// ---------------------------------------------------------------------------
// Pass 1: per-batch fp64 cumsum of durations -> centers, totals. 1 wave/batch.
// (round-0 verbatim)
// ---------------------------------------------------------------------------
__global__ __launch_bounds__(64) void scan_kernel(
    const float* __restrict__ dur,
    float* __restrict__ centers,
    float* __restrict__ totals) {
  int b = blockIdx.x;
  int lane = threadIdx.x;
  const float* d = dur + b * S_TOK;
  int base = lane * 8;
  double local[8];
  double run = 0.0;
#pragma unroll
  for (int i = 0; i < 8; ++i) { run += (double)d[base + i]; local[i] = run; }
  double sum = run;
#pragma unroll
  for (int off = 1; off < 64; off <<= 1) {
    double v = __shfl_up(sum, off, 64);
    if (lane >= off) sum += v;
  }
  double excl = sum - run;
#pragma unroll
  for (int i = 0; i < 8; ++i) {
    centers[b * S_TOK + base + i] =
        (float)(excl + local[i] - 0.5 * (double)d[base + i]);
  }
  if (lane == 63) totals[b] = (float)sum;
}

// ---------------------------------------------------------------------------
// Pass 2: per-frame softmax stats in O(log S + W) (round-0 verbatim),
// plus the mask write folded in (same (b,t) coverage).
// ---------------------------------------------------------------------------
__global__ __launch_bounds__(256) void meta_kernel(
    const float* __restrict__ centers,
    const float* __restrict__ log_sigma,
    const float* __restrict__ totals,
    RowMeta* __restrict__ meta,
    float* __restrict__ mask_out) {
  int b = blockIdx.x >> 3;
  int t = ((blockIdx.x & 7) << 8) + threadIdx.x;

  __shared__ float cbS[S_TOK];
  for (int i = threadIdx.x; i < S_TOK; i += 256)
    cbS[i] = centers[b * S_TOK + i];
  __syncthreads();

  float inv_sigma = expf(-log_sigma[0]);
  float tq = (float)t + 0.5f;

  auto V = [&](int s) {
    float z = (tq - cbS[s]) * inv_sigma;
    return -0.5f * z * z;
  };

  int lo = 0, hi = S_TOK;
  while (lo < hi) {
    int mid = (lo + hi) >> 1;
    if (cbS[mid] < tq) lo = mid + 1; else hi = mid;
  }
  int best; float m;
  if (lo == 0) { best = 0; m = V(0); }
  else if (lo == S_TOK) { best = S_TOK - 1; m = V(best); }
  else {
    float va = V(lo - 1), vb = V(lo);
    if (va >= vb) { best = lo - 1; m = va; } else { best = lo; m = vb; }
  }

  int wl = best, wh = best;
  while (wl > 0 && V(wl - 1) > m + THRESH) --wl;
  while (wh < S_TOK - 1 && V(wh + 1) > m + THRESH) ++wh;

  float l = 0.0f;
  for (int s = wl; s <= wh; ++s) l += expf(V(s) - m);

  RowMeta mt;
  mt.m = m;
  mt.inv_l = 1.0f / l;
  mt.lo = wl;
  mt.cnt = wh - wl + 1;
  meta[b * T_FR + t] = mt;

  mask_out[b * T_FR + t] = ((float)t < totals[b]) ? 1.0f : 0.0f;
}

// ---------------------------------------------------------------------------
// Pass 3: wave-autonomous streaming. 256-thread blocks = 4 independent waves;
// wave w owns frames (t0, t0+1) of one batch. No __syncthreads, no LDS.
// Per token row in the 2-frame union window (~5 rows): load the row's two
// vfloat4 halves (lane, lane+64), compute the 2 exp-weights inline (broadcast
// math, ~12 VALU ops), FMA into 4 vfloat4 accumulators. Store 4x1KB at the
// wave's own pace -> store traffic de-phased across waves/blocks.
// ~55 VGPR -> __launch_bounds__(256,8) = 32 waves/CU.
// ---------------------------------------------------------------------------
__global__ __launch_bounds__(256, 8) void stream_kernel(
    const float* __restrict__ emb,
    const float* __restrict__ centers,
    const float* __restrict__ log_sigma,
    const RowMeta* __restrict__ meta,
    float* __restrict__ x) {
  // XCD swizzle: 8192 blocks; id&7 = XCD slot -> 1024 contiguous-t blocks
  // per XCD = 4 whole batches (4 MB emb slice ~ its L2).
  int id = blockIdx.x;
  int sw = ((id & 7) << 10) + (id >> 3);
  int b = sw >> 8;                 // 256 blocks per batch
  int t0 = ((sw & 255) << 3) + ((threadIdx.x >> 6) << 1);  // wave's 2 frames
  int lane = threadIdx.x & 63;

  RowMeta m0 = meta[b * T_FR + t0];       // broadcast loads (same addr/wave)
  RowMeta m1 = meta[b * T_FR + t0 + 1];
  int ulo = min(m0.lo, m1.lo);
  int uhi = max(m0.lo + m0.cnt, m1.lo + m1.cnt) - 1;
  int cnt = uhi - ulo + 1;               // typ ~4-6; indices in [0,S) by meta

  float inv_sigma = expf(-log_sigma[0]);
  float tq0 = (float)t0 + 0.5f;
  float tq1 = tq0 + 1.0f;

  const float* cb = centers + b * S_TOK + ulo;
  const vfloat4* e4 =
      (const vfloat4*)emb + ((size_t)(b * S_TOK + ulo)) * (E_DIM / 4) + lane;

  vfloat4 a00 = {0.f,0.f,0.f,0.f}, a01 = {0.f,0.f,0.f,0.f};
  vfloat4 a10 = {0.f,0.f,0.f,0.f}, a11 = {0.f,0.f,0.f,0.f};

  // depth-1 software pipeline (TLP at 32 waves/CU covers the rest)
  vfloat4 u0 = e4[0], u1 = e4[64];
  for (int i = 0; i < cnt; ++i) {
    int nx = min(i + 1, cnt - 1) * (E_DIM / 4);
    vfloat4 n0 = e4[nx], n1 = e4[nx + 64];
    float c = cb[i];                     // broadcast, L1-resident
    float z0 = (tq0 - c) * inv_sigma;
    float z1 = (tq1 - c) * inv_sigma;
    float e0 = expf(-0.5f * z0 * z0 - m0.m);   // = exp(v0 - m0), in (0,1]
    float e1 = expf(-0.5f * z1 * z1 - m1.m);
    a00 += e0 * u0;  a01 += e0 * u1;
    a10 += e1 * u0;  a11 += e1 * u1;
    u0 = n0; u1 = n1;
  }

  // Regular cached stores; normalization (1/l_f) folded here (same order as
  // all passing rounds).
  vfloat4* xp = (vfloat4*)x + ((size_t)(b * T_FR + t0)) * (E_DIM / 4) + lane;
  xp[0]       = a00 * m0.inv_l;
  xp[64]      = a01 * m0.inv_l;
  xp[128]     = a10 * m1.inv_l;
  xp[128+64]  = a11 * m1.inv_l;
}

// ---------------------------------------------------------------------------
extern "C" void kernel_launch(void* const* d_in, const int* in_sizes, int n_in,
                              void* d_out, int out_size, void* d_ws,
                              size_t ws_size, hipStream_t stream) {
  const float* emb = (const float*)d_in[0];        // (32, 512, 512)
  const float* dur = (const float*)d_in[1];        // (32, 512)
  const float* log_sigma = (const float*)d_in[2];  // (1,)

  float* x = (float*)d_out;                         // (32, 2048, 512)
  float* mask_out = x + (size_t)BS * T_FR * E_DIM;  // (32, 2048)

  float* centers = (float*)d_ws;              // 64 KB
  float* totals = centers + BS * S_TOK;       // 32 floats (padded to 64)
  RowMeta* meta = (RowMeta*)(totals + 64);    // 65536 * 16 B = 1 MB

  scan_kernel<<<BS, 64, 0, stream>>>(dur, centers, totals);
  meta_kernel<<<BS * 8, 256, 0, stream>>>(centers, log_sigma, totals,
                                          meta, mask_out);
  stream_kernel<<<(BS * T_FR) / 8, 256, 0, stream>>>(
      emb, centers, log_sigma, meta, x);
}

// Round 6
// 171.037 us; speedup vs baseline: 1.0574x; 1.0574x over previous
//
#include <hip/hip_runtime.h>
#include <math.h>

// Problem constants (fixed instance: bs=32, S=512, E=512, T=2048)
#define BS 32
#define S_TOK 512
#define E_DIM 512
#define T_FR 2048
#define FPB 8           // frames per tile
#define NTILE 4         // tiles per block (persistent de-phased blocks)
#define WMAX 20         // union-window clamp for 8 frames (typ ~6-11)
// exp cut: dropped softmax terms < e^-25 of the max term (output perturbation
// ~1e-10 abs; absmax 0.0156 is the bf16-grain ref-rounding floor).
#define THRESH -25.0f

// NOTE: durations never zero -> reference's MASK_FILL branch is identity.

// ROUND 5 POST-MORTEM: wave-autonomous streaming REGRESSED (+15us) -- but it
// confounded store de-phasing with 2x read amplification + loss of LDS weight
// sharing + the known ~5us 3-kernel split cost. R4 (165.6) remains best.
// ROUND 6: un-confounded de-phasing test. R4 structure kept byte-identical in
// traffic/LDS-sharing/XCD-mapping, but: 2048 blocks exactly (8/CU, ONE
// residency round -- no replacement bubbles), each runs NTILE=4 tiles of the
// SAME batch with per-block staggered tile order (rs=id&3) -> at most 1/4 of
// blocks in their store phase at any instant; batch scan amortized 4x.
// If neutral: residual is fixed harness fills + structure-invariant write
// path; declare roofline next round.

typedef float vfloat4 __attribute__((ext_vector_type(4)));

__global__ __launch_bounds__(256, 8) void fused_all(
    const float* __restrict__ emb,
    const float* __restrict__ dur,
    const float* __restrict__ log_sigma,
    float* __restrict__ x,
    float* __restrict__ mask_out) {
  // 2048 blocks; id&7 = XCD slot -> XCD k serves batches 4k..4k+3
  // (4 MB emb slice = its L2; same mapping as R4).
  int id = blockIdx.x;
  int xcd = id & 7;
  int j = id >> 3;                  // 0..255 within XCD
  int b = (xcd << 2) + (j >> 6);    // 4 batches per XCD
  int base = j & 63;                // base tile within batch (0..63)
  int rs = id & 3;                  // per-block tile-phase stagger

  int tid = threadIdx.x;
  int grp = tid >> 7;               // frame group: 0 -> tile frames 0..3, 1 -> 4..7
  int col = tid & 127;              // vfloat4 column owner (E_DIM/4 = 128)

  __shared__ float cbS[S_TOK];                   // centers, 2 KB
  __shared__ __align__(16) float wT[WMAX][FPB];  // raw exp weights, 640 B
  __shared__ float mS[FPB];                      // per-frame max
  __shared__ float invS[FPB];                    // per-frame 1/sum
  __shared__ double wsumS[4];
  __shared__ int uloS, cntS;
  __shared__ float totalS;

  float inv_sigma = expf(-log_sigma[0]);

  // ---- stage 1 (ONCE per block): fp64 cumsum of batch durations ----
  {
    const float* dp = dur + b * S_TOK;
    int i2 = tid << 1;
    double d0 = (double)dp[i2];
    double d1 = (double)dp[i2 + 1];
    double pair = d0 + d1;
    double run = pair;                  // wave-inclusive scan of pair sums
#pragma unroll
    for (int off = 1; off < 64; off <<= 1) {
      double v = __shfl_up(run, off, 64);
      if ((tid & 63) >= off) run += v;
    }
    int w = tid >> 6;
    if ((tid & 63) == 63) wsumS[w] = run;
    __syncthreads();
    double wexcl = 0.0;
#pragma unroll
    for (int k = 0; k < 3; ++k) wexcl += (k < w) ? wsumS[k] : 0.0;
    double incl = wexcl + run;          // inclusive cumsum through this pair
    double excl = incl - pair;          // exclusive before this pair
    cbS[i2]     = (float)(excl + d0 - 0.5 * d0);
    cbS[i2 + 1] = (float)(excl + (d0 + d1) - 0.5 * d1);
    if (tid == 255) totalS = (float)incl;
  }
  __syncthreads();   // cbS, totalS ready for all tiles

  // ---- NTILE tiles, per-block staggered order ----
  for (int k = 0; k < NTILE; ++k) {
    int t0 = (base + (((rs + k) & 3) << 6)) << 3;   // tile start frame

    // -- stage 2 (wave 0): per-frame binary search + ballot window probe --
    if (tid < 64) {
      int l = tid;
      float tq0 = (float)t0 + 0.5f;
      float tq7 = (float)t0 + 7.5f;
      int best = 0;
      float m = 0.0f;
      if (l < FPB) {
        float tqf = (float)(t0 + l) + 0.5f;
        int lo = 0, hi = S_TOK;
        while (lo < hi) {
          int mid = (lo + hi) >> 1;
          if (cbS[mid] < tqf) lo = mid + 1; else hi = mid;
        }
        if (lo == 0) {
          best = 0;
          float z = (tqf - cbS[0]) * inv_sigma; m = -0.5f * z * z;
        } else if (lo == S_TOK) {
          best = S_TOK - 1;
          float z = (tqf - cbS[best]) * inv_sigma; m = -0.5f * z * z;
        } else {
          float za = (tqf - cbS[lo - 1]) * inv_sigma; float va = -0.5f * za * za;
          float zb = (tqf - cbS[lo]) * inv_sigma;     float vb = -0.5f * zb * zb;
          if (va >= vb) { best = lo - 1; m = va; } else { best = lo; m = vb; }
        }
        mS[l] = m;
      }
      // union edges: frame 0 lower, frame 7 upper (edges monotone in f);
      // 16-lane ballot probe each (flags monotone away from the peak).
      int best0 = __shfl(best, 0, 64);  float m0 = __shfl(m, 0, 64);
      int best7 = __shfl(best, 7, 64);  float m7 = __shfl(m, 7, 64);
      int p = l & 15;
      bool flag = false;
      if (l < 16) {
        int s = best0 - 1 - p;
        if (s >= 0) {
          float z = (tq0 - cbS[s]) * inv_sigma;
          flag = (-0.5f * z * z) > m0 + THRESH;
        }
      } else if (l < 32) {
        int s = best7 + 1 + p;
        if (s < S_TOK) {
          float z = (tq7 - cbS[s]) * inv_sigma;
          flag = (-0.5f * z * z) > m7 + THRESH;
        }
      }
      unsigned long long bal = __ballot(flag);
      if (l == 0) {
        int wl = best0 - __popcll(bal & 0xFFFFull);
        int wh = best7 + __popcll(bal & 0xFFFF0000ull);
        uloS = wl;
        cntS = min(wh - wl + 1, WMAX);  // clamp = memory-safety only
      }
    }
    __syncthreads();

    int ulo = uloS, cnt = cntS;

    // prefetch first two emb rows; latency hides under the weights pass
    const vfloat4* e4 =
        (const vfloat4*)emb + ((size_t)(b * S_TOK + ulo)) * (E_DIM / 4) + col;
    vfloat4 vcur = e4[0];
    vfloat4 vnext = e4[(size_t)min(1, cnt - 1) * (E_DIM / 4)];

    // -- weights: raw exp(v - m_f); cnt*8 <= 160 items -> single pass --
    if (tid < cnt * FPB) {
      int i = tid >> 3, f = tid & 7;
      float c = cbS[ulo + i];
      float tqf = (float)(t0 + f) + 0.5f;
      float z = (tqf - c) * inv_sigma;
      wT[i][f] = expf(-0.5f * z * z - mS[f]);   // v<=m -> exp in (0,1]
    }
    __syncthreads();

    // -- per-frame sums (32 lanes per frame), 1/l into invS --
    {
      int f = tid >> 5, p = tid & 31;
      float s = 0.0f;
      for (int i = p; i < cnt; i += 32) s += wT[i][f];
#pragma unroll
      for (int off = 1; off < 32; off <<= 1) s += __shfl_xor(s, off, 64);
      if (p == 0) invS[f] = 1.0f / s;   // s >= exp(0)=1
    }
    __syncthreads();

    // -- sparse weighted sum: 4 vfloat4 accumulators, depth-2 prefetch --
    vfloat4 acc0 = {0.f,0.f,0.f,0.f}, acc1 = {0.f,0.f,0.f,0.f};
    vfloat4 acc2 = {0.f,0.f,0.f,0.f}, acc3 = {0.f,0.f,0.f,0.f};

    for (int i = 0; i < cnt; ++i) {
      vfloat4 vfut = e4[(size_t)min(i + 2, cnt - 1) * (E_DIM / 4)];
      vfloat4 w = *(const vfloat4*)&wT[i][grp << 2];  // broadcast read
      acc0 += w.x * vcur;
      acc1 += w.y * vcur;
      acc2 += w.z * vcur;
      acc3 += w.w * vcur;
      vcur = vnext; vnext = vfut;
    }

    // Regular cached stores; normalization (1/l_f) folded in here.
    int f0 = grp << 2;
    vfloat4* xp = (vfloat4*)x +
        ((size_t)(b * T_FR + t0 + f0)) * (E_DIM / 4) + col;
    xp[0 * (E_DIM / 4)] = acc0 * invS[f0 + 0];
    xp[1 * (E_DIM / 4)] = acc1 * invS[f0 + 1];
    xp[2 * (E_DIM / 4)] = acc2 * invS[f0 + 2];
    xp[3 * (E_DIM / 4)] = acc3 * invS[f0 + 3];

    if (tid < FPB) {
      int t = t0 + tid;
      mask_out[b * T_FR + t] = ((float)t < totalS) ? 1.0f : 0.0f;
    }
    // No end-of-tile barrier needed: next tile's stage-2 (wave 0) writes only
    // mS/uloS/cntS, none of which are read by the accumulate/store phase
    // (ulo/cnt already in registers; wT/invS untouched until after the next
    // barriers) -- lets wave 0 run ahead, adding further desync.
  }
}

// ---------------------------------------------------------------------------
extern "C" void kernel_launch(void* const* d_in, const int* in_sizes, int n_in,
                              void* d_out, int out_size, void* d_ws,
                              size_t ws_size, hipStream_t stream) {
  const float* emb = (const float*)d_in[0];        // (32, 512, 512)
  const float* dur = (const float*)d_in[1];        // (32, 512)
  const float* log_sigma = (const float*)d_in[2];  // (1,)

  float* x = (float*)d_out;                         // (32, 2048, 512)
  float* mask_out = x + (size_t)BS * T_FR * E_DIM;  // (32, 2048)

  fused_all<<<(BS * T_FR) / (FPB * NTILE), 256, 0, stream>>>(
      emb, dur, log_sigma, x, mask_out);
}